// Round 2
// baseline (4189.198 us; speedup 1.0000x reference)
//
#include <hip/hip_runtime.h>
#include <cstdint>

namespace {
constexpr int kNUsers = 50000;
constexpr int kNTotal = 100000;        // N = users + items
constexpr int kD = 64;
constexpr int kHops = 3;
constexpr int kNnz = 3200000;
constexpr int kRowStride = (kHops + 1) * kD;     // 256 floats per node in embs
}

#define ROTL32(v, r) (((v) << (r)) | ((v) >> (32 - (r))))

// JAX threefry2x32, 20 rounds — matches jax/_src/prng.py exactly.
__host__ __device__ inline void tf2x32(uint32_t k0, uint32_t k1,
                                       uint32_t &x0, uint32_t &x1) {
  const uint32_t k2 = k0 ^ k1 ^ 0x1BD11BDAu;
  x0 += k0; x1 += k1;
#define TFR(r) { x0 += x1; x1 = ROTL32(x1, r); x1 ^= x0; }
  TFR(13) TFR(15) TFR(26) TFR(6)
  x0 += k1; x1 += k2 + 1u;
  TFR(17) TFR(29) TFR(16) TFR(24)
  x0 += k2; x1 += k0 + 2u;
  TFR(13) TFR(15) TFR(26) TFR(6)
  x0 += k0; x1 += k1 + 3u;
  TFR(17) TFR(29) TFR(16) TFR(24)
  x0 += k1; x1 += k2 + 4u;
  TFR(13) TFR(15) TFR(26) TFR(6)
  x0 += k2; x1 += k0 + 5u;
#undef TFR
}

// partitionable random_bits for 32-bit draws: counter (0, i), fold x0^x1
__device__ __forceinline__ uint32_t pbits(uint32_t k0, uint32_t k1, uint32_t i) {
  uint32_t x0 = 0u, x1 = i;
  tf2x32(k0, k1, x0, x1);
  return x0 ^ x1;
}

// bits -> U[0,1) exactly like jax.random.uniform (f32): (b>>9)|0x3f800000, -1.0
__device__ __forceinline__ float u01(uint32_t b) {
  return __uint_as_float((b >> 9) | 0x3f800000u) - 1.0f;
}

// embs[:,0,:] = concat(user, item); embs[:,1:4,:] = 0. One thread per (node, float4).
__global__ void k_init(const float* __restrict__ ue, const float* __restrict__ ie,
                       float* __restrict__ out) {
  int t = blockIdx.x * blockDim.x + threadIdx.x;
  if (t >= kNTotal * 16) return;
  int n = t >> 4, c = t & 15;
  float4 v = (n < kNUsers) ? reinterpret_cast<const float4*>(ue)[n * 16 + c]
                           : reinterpret_cast<const float4*>(ie)[(n - kNUsers) * 16 + c];
  float4* orow = reinterpret_cast<float4*>(out) + (size_t)n * (kRowStride / 4);
  const float4 z = make_float4(0.f, 0.f, 0.f, 0.f);
  orow[c] = v;          // hop-0 slice
  orow[16 + c] = z;     // hop-1 slice (accumulator)
  orow[32 + c] = z;     // hop-2
  orow[48 + c] = z;     // hop-3
}

// v[e] = keep(e) ? vals[e]*2 : 0 ; one thread per edge (partitionable bits)
__global__ void k_edgedrop(const float* __restrict__ vals, float* __restrict__ v,
                           uint32_t k0, uint32_t k1) {
  int i = blockIdx.x * blockDim.x + threadIdx.x;
  if (i >= kNnz) return;
  float u = u01(pbits(k0, k1, (uint32_t)i));
  v[i] = (u >= 0.5f) ? vals[i] * 2.0f : 0.0f;
}

// scatter SpMM: thread per (edge, float4-chunk); src/dst point at hop slices.
__global__ void k_spmm(const float* __restrict__ vv, const int* __restrict__ rows,
                       const int* __restrict__ cols,
                       const float* __restrict__ src, float* __restrict__ dst) {
  long long t = (long long)blockIdx.x * blockDim.x + threadIdx.x;
  if (t >= (long long)kNnz * 16) return;
  int e = (int)(t >> 4), c = (int)(t & 15);
  float val = vv[e];
  if (val == 0.0f) return;
  int r = rows[e], col = cols[e];
  float4 a = *reinterpret_cast<const float4*>(src + (size_t)col * kRowStride + c * 4);
  float* d = dst + (size_t)r * kRowStride + c * 4;
  unsafeAtomicAdd(d + 0, val * a.x);
  unsafeAtomicAdd(d + 1, val * a.y);
  unsafeAtomicAdd(d + 2, val * a.z);
  unsafeAtomicAdd(d + 3, val * a.w);
}

// message dropout in-place on a hop slice; flat (N,D) element j (partitionable)
__global__ void k_messdrop(float* __restrict__ dst, uint32_t k0, uint32_t k1) {
  int j = blockIdx.x * blockDim.x + threadIdx.x;
  if (j >= kNTotal * kD) return;
  float u = u01(pbits(k0, k1, (uint32_t)j));
  size_t a = (size_t)(j >> 6) * kRowStride + (j & 63);
  float x = dst[a];
  dst[a] = (u < 0.9f) ? x * (float)(1.0 / 0.9) : 0.0f;
}

extern "C" void kernel_launch(void* const* d_in, const int* in_sizes, int n_in,
                              void* d_out, int out_size, void* d_ws, size_t ws_size,
                              hipStream_t stream) {
  const float* ue = (const float*)d_in[0];
  const float* ie = (const float*)d_in[1];
  const float* ev = (const float*)d_in[2];
  const int*   er = (const int*)d_in[3];
  const int*   ec = (const int*)d_in[4];
  float* out = (float*)d_out;
  float* v   = (float*)d_ws;   // kNnz floats = 12.8 MB scratch

  // host-side keys: base = key(42) = (0,42); per hop fold_in, then
  // partitionable ("foldlike") split: keys[j] = threefry(key, (0, j)).
  uint32_t ke0[kHops], ke1[kHops], km0[kHops], km1[kHops];
  for (int hop = 0; hop < kHops; ++hop) {
    uint32_t f0 = 0u, f1 = (uint32_t)hop;
    tf2x32(0u, 42u, f0, f1);                 // fold_in: threefry(key, (0,hop))
    uint32_t e0 = 0u, e1 = 0u;               // split[0]: counter (0,0)
    tf2x32(f0, f1, e0, e1);
    uint32_t m0 = 0u, m1 = 1u;               // split[1]: counter (0,1)
    tf2x32(f0, f1, m0, m1);
    ke0[hop] = e0; ke1[hop] = e1;
    km0[hop] = m0; km1[hop] = m1;
  }

  const int BS = 256;
  k_init<<<(kNTotal * 16 + BS - 1) / BS, BS, 0, stream>>>(ue, ie, out);

  for (int hop = 0; hop < kHops; ++hop) {
    k_edgedrop<<<(kNnz + BS - 1) / BS, BS, 0, stream>>>(ev, v, ke0[hop], ke1[hop]);
    const float* src = out + (size_t)hop * kD;        // embs[:,hop,:]
    float*       dst = out + (size_t)(hop + 1) * kD;  // embs[:,hop+1,:]
    long long spmm_threads = (long long)kNnz * 16;
    k_spmm<<<(int)((spmm_threads + BS - 1) / BS), BS, 0, stream>>>(v, er, ec, src, dst);
    k_messdrop<<<(kNTotal * kD + BS - 1) / BS, BS, 0, stream>>>(dst, km0[hop], km1[hop]);
  }
}

// Round 3
// 899.102 us; speedup vs baseline: 4.6593x; 4.6593x over previous
//
#include <hip/hip_runtime.h>
#include <cstdint>

namespace {
constexpr int kNUsers = 50000;
constexpr int kNTotal = 100000;        // N = users + items
constexpr int kD = 64;
constexpr int kHops = 3;
constexpr int kNnz = 3200000;
constexpr int kRowStride = (kHops + 1) * kD;     // 256 floats per node in embs
}

#define ROTL32(v, r) (((v) << (r)) | ((v) >> (32 - (r))))

// JAX threefry2x32, 20 rounds — matches jax/_src/prng.py exactly.
__host__ __device__ inline void tf2x32(uint32_t k0, uint32_t k1,
                                       uint32_t &x0, uint32_t &x1) {
  const uint32_t k2 = k0 ^ k1 ^ 0x1BD11BDAu;
  x0 += k0; x1 += k1;
#define TFR(r) { x0 += x1; x1 = ROTL32(x1, r); x1 ^= x0; }
  TFR(13) TFR(15) TFR(26) TFR(6)
  x0 += k1; x1 += k2 + 1u;
  TFR(17) TFR(29) TFR(16) TFR(24)
  x0 += k2; x1 += k0 + 2u;
  TFR(13) TFR(15) TFR(26) TFR(6)
  x0 += k0; x1 += k1 + 3u;
  TFR(17) TFR(29) TFR(16) TFR(24)
  x0 += k1; x1 += k2 + 4u;
  TFR(13) TFR(15) TFR(26) TFR(6)
  x0 += k2; x1 += k0 + 5u;
#undef TFR
}

// partitionable random_bits for 32-bit draws: counter (0, i), fold x0^x1
__device__ __forceinline__ uint32_t pbits(uint32_t k0, uint32_t k1, uint32_t i) {
  uint32_t x0 = 0u, x1 = i;
  tf2x32(k0, k1, x0, x1);
  return x0 ^ x1;
}

// bits -> U[0,1) exactly like jax.random.uniform (f32): (b>>9)|0x3f800000, -1.0
__device__ __forceinline__ float u01(uint32_t b) {
  return __uint_as_float((b >> 9) | 0x3f800000u) - 1.0f;
}

// embs[:,0,:] = concat(user, item). One thread per (node, float4).
// (hop 1..3 slices are fully overwritten by k_spmm_csr — no zeroing needed)
__global__ void k_init(const float* __restrict__ ue, const float* __restrict__ ie,
                       float* __restrict__ out) {
  int t = blockIdx.x * blockDim.x + threadIdx.x;
  if (t >= kNTotal * 16) return;
  int n = t >> 4, c = t & 15;
  float4 v = (n < kNUsers) ? reinterpret_cast<const float4*>(ue)[n * 16 + c]
                           : reinterpret_cast<const float4*>(ie)[(n - kNUsers) * 16 + c];
  reinterpret_cast<float4*>(out)[(size_t)n * (kRowStride / 4) + c] = v;
}

// ---------------- CSR build (per call; ~200 µs) ----------------
__global__ void k_zero_cnt(int* __restrict__ cnt) {
  int t = blockIdx.x * blockDim.x + threadIdx.x;
  if (t < kNTotal) cnt[t] = 0;
}

__global__ void k_hist(const int* __restrict__ rows, int* __restrict__ cnt) {
  int e = blockIdx.x * blockDim.x + threadIdx.x;
  if (e < kNnz) atomicAdd(&cnt[rows[e]], 1);
}

// single-block exclusive scan of cnt[100000] -> row_ptr; resets cnt to 0
__global__ void k_scan(int* __restrict__ row_ptr, int* __restrict__ cnt) {
  __shared__ int part[1024];
  const int t = threadIdx.x;
  const int chunk = (kNTotal + 1023) / 1024;   // 98
  int lo = t * chunk, hi = min(lo + chunk, kNTotal);
  int s = 0;
  for (int r = lo; r < hi; ++r) s += cnt[r];
  part[t] = s;
  __syncthreads();
  for (int off = 1; off < 1024; off <<= 1) {
    int add = (t >= off) ? part[t - off] : 0;
    __syncthreads();
    part[t] += add;
    __syncthreads();
  }
  int run = (t == 0) ? 0 : part[t - 1];
  for (int r = lo; r < hi; ++r) { int c = cnt[r]; row_ptr[r] = run; run += c; cnt[r] = 0; }
  if (t == 1023) row_ptr[kNTotal] = part[1023];
}

__global__ void k_scatter(const int* __restrict__ rows, const int* __restrict__ cols,
                          const float* __restrict__ vals,
                          const int* __restrict__ row_ptr, int* __restrict__ cnt,
                          int* __restrict__ csr_col, int* __restrict__ csr_id,
                          float* __restrict__ csr_val) {
  int e = blockIdx.x * blockDim.x + threadIdx.x;
  if (e >= kNnz) return;
  int r = rows[e];
  int pos = row_ptr[r] + atomicAdd(&cnt[r], 1);
  csr_col[pos] = cols[e];
  csr_id[pos] = e;
  csr_val[pos] = vals[e];
}

// ---------------- fused SpMM: one wave per row ----------------
// lane d accumulates output column d in a register; edge-dropout threefry is
// computed lane-parallel over 64-edge chunks and broadcast via per-wave LDS;
// message dropout fused into the store. No atomics, single write per element.
__global__ __launch_bounds__(256) void k_spmm_csr(
    const int* __restrict__ row_ptr, const int* __restrict__ csr_col,
    const int* __restrict__ csr_id, const float* __restrict__ csr_val,
    const float* __restrict__ src, float* __restrict__ dst,
    uint32_t ke0, uint32_t ke1, uint32_t km0, uint32_t km1) {
  __shared__ int2 stage[4][64];
  const int wave = threadIdx.x >> 6;
  const int lane = threadIdx.x & 63;
  const int r = blockIdx.x * 4 + wave;
  if (r >= kNTotal) return;
  const int start = row_ptr[r], end = row_ptr[r + 1];
  float acc = 0.f;
  for (int base = start; base < end; base += 64) {
    const int n = min(64, end - base);
    int2 cv = make_int2(0, 0);
    if (lane < n) {
      const int e = base + lane;
      const int col = csr_col[e];
      const int id = csr_id[e];
      const float val = csr_val[e];
      const float u = u01(pbits(ke0, ke1, (uint32_t)id));
      cv = make_int2(col, __float_as_int(u >= 0.5f ? val * 2.0f : 0.0f));
    }
    stage[wave][lane] = cv;   // wave-synchronous; compiler inserts lgkmcnt wait
    for (int j = 0; j < n; ++j) {
      const int2 s2 = stage[wave][j];
      const float v = __int_as_float(s2.y);
      if (v != 0.0f)          // wave-uniform branch (~50% of edges skipped)
        acc += v * src[(size_t)s2.x * kRowStride + lane];
    }
  }
  // fused message dropout + single coalesced store
  const float u = u01(pbits(km0, km1, (uint32_t)(r * 64 + lane)));
  dst[(size_t)r * kRowStride + lane] = (u < 0.9f) ? acc * (float)(1.0 / 0.9) : 0.0f;
}

// ---------------- fallback (round-2 atomic path) ----------------
__global__ void k_edgedrop(const float* __restrict__ vals, float* __restrict__ v,
                           uint32_t k0, uint32_t k1) {
  int i = blockIdx.x * blockDim.x + threadIdx.x;
  if (i >= kNnz) return;
  float u = u01(pbits(k0, k1, (uint32_t)i));
  v[i] = (u >= 0.5f) ? vals[i] * 2.0f : 0.0f;
}

__global__ void k_zero_hop(float* __restrict__ dst) {
  int t = blockIdx.x * blockDim.x + threadIdx.x;
  if (t >= kNTotal * kD) return;
  dst[(size_t)(t >> 6) * kRowStride + (t & 63)] = 0.f;
}

__global__ void k_spmm_atomic(const float* __restrict__ vv, const int* __restrict__ rows,
                              const int* __restrict__ cols,
                              const float* __restrict__ src, float* __restrict__ dst) {
  long long t = (long long)blockIdx.x * blockDim.x + threadIdx.x;
  if (t >= (long long)kNnz * 16) return;
  int e = (int)(t >> 4), c = (int)(t & 15);
  float val = vv[e];
  if (val == 0.0f) return;
  int r = rows[e], col = cols[e];
  float4 a = *reinterpret_cast<const float4*>(src + (size_t)col * kRowStride + c * 4);
  float* d = dst + (size_t)r * kRowStride + c * 4;
  unsafeAtomicAdd(d + 0, val * a.x);
  unsafeAtomicAdd(d + 1, val * a.y);
  unsafeAtomicAdd(d + 2, val * a.z);
  unsafeAtomicAdd(d + 3, val * a.w);
}

__global__ void k_messdrop(float* __restrict__ dst, uint32_t k0, uint32_t k1) {
  int j = blockIdx.x * blockDim.x + threadIdx.x;
  if (j >= kNTotal * kD) return;
  float u = u01(pbits(k0, k1, (uint32_t)j));
  size_t a = (size_t)(j >> 6) * kRowStride + (j & 63);
  float x = dst[a];
  dst[a] = (u < 0.9f) ? x * (float)(1.0 / 0.9) : 0.0f;
}

extern "C" void kernel_launch(void* const* d_in, const int* in_sizes, int n_in,
                              void* d_out, int out_size, void* d_ws, size_t ws_size,
                              hipStream_t stream) {
  const float* ue = (const float*)d_in[0];
  const float* ie = (const float*)d_in[1];
  const float* ev = (const float*)d_in[2];
  const int*   er = (const int*)d_in[3];
  const int*   ec = (const int*)d_in[4];
  float* out = (float*)d_out;

  // keys: base = key(42) = (0,42); per hop fold_in, then partitionable split:
  // keys[j] = threefry(folded_key, (0, j)).
  uint32_t ke0[kHops], ke1[kHops], km0[kHops], km1[kHops];
  for (int hop = 0; hop < kHops; ++hop) {
    uint32_t f0 = 0u, f1 = (uint32_t)hop;
    tf2x32(0u, 42u, f0, f1);
    uint32_t e0 = 0u, e1 = 0u;
    tf2x32(f0, f1, e0, e1);
    uint32_t m0 = 0u, m1 = 1u;
    tf2x32(f0, f1, m0, m1);
    ke0[hop] = e0; ke1[hop] = e1;
    km0[hop] = m0; km1[hop] = m1;
  }

  const int BS = 256;

  // ws layout (ints): row_ptr[100001] | cnt[100000] | pad | csr_col[NNZ] | csr_id[NNZ] | csr_val[NNZ]
  const size_t off_rowptr = 0;
  const size_t off_cnt    = 100001;
  const size_t off_csr    = 200004;                 // 16B aligned
  const size_t needed = (off_csr + 3 * (size_t)kNnz) * 4;

  k_init<<<(kNTotal * 16 + BS - 1) / BS, BS, 0, stream>>>(ue, ie, out);

  if (ws_size >= needed) {
    int*   row_ptr = (int*)d_ws + off_rowptr;
    int*   cnt     = (int*)d_ws + off_cnt;
    int*   csr_col = (int*)d_ws + off_csr;
    int*   csr_id  = csr_col + kNnz;
    float* csr_val = (float*)(csr_id + kNnz);

    k_zero_cnt<<<(kNTotal + BS - 1) / BS, BS, 0, stream>>>(cnt);
    k_hist<<<(kNnz + BS - 1) / BS, BS, 0, stream>>>(er, cnt);
    k_scan<<<1, 1024, 0, stream>>>(row_ptr, cnt);
    k_scatter<<<(kNnz + BS - 1) / BS, BS, 0, stream>>>(er, ec, ev, row_ptr, cnt,
                                                       csr_col, csr_id, csr_val);
    for (int hop = 0; hop < kHops; ++hop) {
      const float* src = out + (size_t)hop * kD;
      float*       dst = out + (size_t)(hop + 1) * kD;
      k_spmm_csr<<<(kNTotal + 3) / 4, 256, 0, stream>>>(
          row_ptr, csr_col, csr_id, csr_val, src, dst,
          ke0[hop], ke1[hop], km0[hop], km1[hop]);
    }
  } else {
    // fallback: atomic scatter path (round 2)
    float* v = (float*)d_ws;
    for (int hop = 0; hop < kHops; ++hop) {
      const float* src = out + (size_t)hop * kD;
      float*       dst = out + (size_t)(hop + 1) * kD;
      k_edgedrop<<<(kNnz + BS - 1) / BS, BS, 0, stream>>>(ev, v, ke0[hop], ke1[hop]);
      k_zero_hop<<<(kNTotal * kD + BS - 1) / BS, BS, 0, stream>>>(dst);
      long long spmm_threads = (long long)kNnz * 16;
      k_spmm_atomic<<<(int)((spmm_threads + BS - 1) / BS), BS, 0, stream>>>(v, er, ec, src, dst);
      k_messdrop<<<(kNTotal * kD + BS - 1) / BS, BS, 0, stream>>>(dst, km0[hop], km1[hop]);
    }
  }
}

// Round 4
// 740.823 us; speedup vs baseline: 5.6548x; 1.2137x over previous
//
#include <hip/hip_runtime.h>
#include <cstdint>

namespace {
constexpr int kNUsers = 50000;
constexpr int kNTotal = 100000;        // N = users + items
constexpr int kD = 64;
constexpr int kHops = 3;
constexpr int kNnz = 3200000;
constexpr int kRowStride = (kHops + 1) * kD;     // 256 floats per node in embs
constexpr uint32_t kColMask = (1u << 20) - 1u;   // col in bits 0..19, keep bits 20..22
}

#define ROTL32(v, r) (((v) << (r)) | ((v) >> (32 - (r))))

// JAX threefry2x32, 20 rounds — matches jax/_src/prng.py exactly.
__host__ __device__ inline void tf2x32(uint32_t k0, uint32_t k1,
                                       uint32_t &x0, uint32_t &x1) {
  const uint32_t k2 = k0 ^ k1 ^ 0x1BD11BDAu;
  x0 += k0; x1 += k1;
#define TFR(r) { x0 += x1; x1 = ROTL32(x1, r); x1 ^= x0; }
  TFR(13) TFR(15) TFR(26) TFR(6)
  x0 += k1; x1 += k2 + 1u;
  TFR(17) TFR(29) TFR(16) TFR(24)
  x0 += k2; x1 += k0 + 2u;
  TFR(13) TFR(15) TFR(26) TFR(6)
  x0 += k0; x1 += k1 + 3u;
  TFR(17) TFR(29) TFR(16) TFR(24)
  x0 += k1; x1 += k2 + 4u;
  TFR(13) TFR(15) TFR(26) TFR(6)
  x0 += k2; x1 += k0 + 5u;
#undef TFR
}

// partitionable random_bits for 32-bit draws: counter (0, i), fold x0^x1
__device__ __forceinline__ uint32_t pbits(uint32_t k0, uint32_t k1, uint32_t i) {
  uint32_t x0 = 0u, x1 = i;
  tf2x32(k0, k1, x0, x1);
  return x0 ^ x1;
}

// bits -> U[0,1) exactly like jax.random.uniform (f32): (b>>9)|0x3f800000, -1.0
__device__ __forceinline__ float u01(uint32_t b) {
  return __uint_as_float((b >> 9) | 0x3f800000u) - 1.0f;
}

// embs[:,0,:] = concat(user, item). One thread per (node, float4).
__global__ void k_init(const float* __restrict__ ue, const float* __restrict__ ie,
                       float* __restrict__ out) {
  int t = blockIdx.x * blockDim.x + threadIdx.x;
  if (t >= kNTotal * 16) return;
  int n = t >> 4, c = t & 15;
  float4 v = (n < kNUsers) ? reinterpret_cast<const float4*>(ue)[n * 16 + c]
                           : reinterpret_cast<const float4*>(ie)[(n - kNUsers) * 16 + c];
  reinterpret_cast<float4*>(out)[(size_t)n * (kRowStride / 4) + c] = v;
}

// ---------------- CSR build ----------------
__global__ void k_zero_cnt(int* __restrict__ cnt) {
  int t = blockIdx.x * blockDim.x + threadIdx.x;
  if (t < kNTotal) cnt[t] = 0;
}

__global__ void k_hist(const int* __restrict__ rows, int* __restrict__ cnt) {
  int e = blockIdx.x * blockDim.x + threadIdx.x;
  if (e < kNnz) atomicAdd(&cnt[rows[e]], 1);
}

// single-block exclusive scan of cnt[100000] -> row_ptr; resets cnt to 0
__global__ void k_scan(int* __restrict__ row_ptr, int* __restrict__ cnt) {
  __shared__ int part[1024];
  const int t = threadIdx.x;
  const int chunk = (kNTotal + 1023) / 1024;   // 98
  int lo = t * chunk, hi = min(lo + chunk, kNTotal);
  int s = 0;
  for (int r = lo; r < hi; ++r) s += cnt[r];
  part[t] = s;
  __syncthreads();
  for (int off = 1; off < 1024; off <<= 1) {
    int add = (t >= off) ? part[t - off] : 0;
    __syncthreads();
    part[t] += add;
    __syncthreads();
  }
  int run = (t == 0) ? 0 : part[t - 1];
  for (int r = lo; r < hi; ++r) { int c = cnt[r]; row_ptr[r] = run; run += c; cnt[r] = 0; }
  if (t == 1023) row_ptr[kNTotal] = part[1023];
}

// packed scatter: one int2 per edge = {col | keepbits<<20, val*2}.
// keep bits for all 3 hops computed here (threefry on original edge id e),
// so SpMM needs no RNG per edge and only ONE dirty line per edge.
__global__ void k_scatter(const int* __restrict__ rows, const int* __restrict__ cols,
                          const float* __restrict__ vals,
                          const int* __restrict__ row_ptr, int* __restrict__ cnt,
                          int2* __restrict__ csr,
                          uint32_t ke0_0, uint32_t ke1_0,
                          uint32_t ke0_1, uint32_t ke1_1,
                          uint32_t ke0_2, uint32_t ke1_2) {
  int e = blockIdx.x * blockDim.x + threadIdx.x;
  if (e >= kNnz) return;
  int r = rows[e];
  int pos = row_ptr[r] + atomicAdd(&cnt[r], 1);
  uint32_t x = (uint32_t)cols[e];
  if (u01(pbits(ke0_0, ke1_0, (uint32_t)e)) >= 0.5f) x |= 1u << 20;
  if (u01(pbits(ke0_1, ke1_1, (uint32_t)e)) >= 0.5f) x |= 1u << 21;
  if (u01(pbits(ke0_2, ke1_2, (uint32_t)e)) >= 0.5f) x |= 1u << 22;
  csr[pos] = make_int2((int)x, __float_as_int(vals[e] * 2.0f));
}

// ---------------- fused SpMM: one wave per row ----------------
// ballot-compacts kept edges into the LDS stage, then a 4-way unrolled
// broadcast+gather loop with 4 independent accumulators (no branch, no RNG).
// Message dropout fused into the single coalesced store.
__global__ __launch_bounds__(256) void k_spmm_csr(
    const int* __restrict__ row_ptr, const int2* __restrict__ csr,
    const float* __restrict__ src, float* __restrict__ dst,
    uint32_t hopbit, uint32_t km0, uint32_t km1) {
  __shared__ int2 stage[4][68];
  const int wave = threadIdx.x >> 6;
  const int lane = threadIdx.x & 63;
  const int r = __builtin_amdgcn_readfirstlane(blockIdx.x * 4 + wave);
  if (r >= kNTotal) return;
  const int start = row_ptr[r], end = row_ptr[r + 1];
  float a0 = 0.f, a1 = 0.f, a2 = 0.f, a3 = 0.f;
  for (int base = start; base < end; base += 64) {
    const int n = min(64, end - base);
    bool keep = false;
    int2 cv = make_int2(0, 0);
    if (lane < n) {
      cv = csr[base + lane];
      keep = ((uint32_t)cv.x & hopbit) != 0u;
    }
    const uint64_t m = __ballot(keep);
    const int k = __popcll(m);
    if (keep) {
      const int slot = __popcll(m & ((1ull << lane) - 1ull));
      stage[wave][slot] = make_int2((int)((uint32_t)cv.x & kColMask), cv.y);
    }
    if (lane < 3) stage[wave][k + lane] = make_int2(0, 0);  // zero-pad for unroll tail
    // wave-synchronous LDS (single wave writes+reads its own stage row)
    for (int j = 0; j < k; j += 4) {
      const int2 e0 = stage[wave][j];
      const int2 e1 = stage[wave][j + 1];
      const int2 e2 = stage[wave][j + 2];
      const int2 e3 = stage[wave][j + 3];
      a0 += __int_as_float(e0.y) * src[(size_t)e0.x * kRowStride + lane];
      a1 += __int_as_float(e1.y) * src[(size_t)e1.x * kRowStride + lane];
      a2 += __int_as_float(e2.y) * src[(size_t)e2.x * kRowStride + lane];
      a3 += __int_as_float(e3.y) * src[(size_t)e3.x * kRowStride + lane];
    }
  }
  const float acc = (a0 + a1) + (a2 + a3);
  // fused message dropout + single coalesced store
  const float u = u01(pbits(km0, km1, (uint32_t)(r * 64 + lane)));
  dst[(size_t)r * kRowStride + lane] = (u < 0.9f) ? acc * (float)(1.0 / 0.9) : 0.0f;
}

extern "C" void kernel_launch(void* const* d_in, const int* in_sizes, int n_in,
                              void* d_out, int out_size, void* d_ws, size_t ws_size,
                              hipStream_t stream) {
  const float* ue = (const float*)d_in[0];
  const float* ie = (const float*)d_in[1];
  const float* ev = (const float*)d_in[2];
  const int*   er = (const int*)d_in[3];
  const int*   ec = (const int*)d_in[4];
  float* out = (float*)d_out;

  // keys: base = key(42) = (0,42); per hop fold_in, then partitionable split:
  // keys[j] = threefry(folded_key, (0, j)).
  uint32_t ke0[kHops], ke1[kHops], km0[kHops], km1[kHops];
  for (int hop = 0; hop < kHops; ++hop) {
    uint32_t f0 = 0u, f1 = (uint32_t)hop;
    tf2x32(0u, 42u, f0, f1);
    uint32_t e0 = 0u, e1 = 0u;
    tf2x32(f0, f1, e0, e1);
    uint32_t m0 = 0u, m1 = 1u;
    tf2x32(f0, f1, m0, m1);
    ke0[hop] = e0; ke1[hop] = e1;
    km0[hop] = m0; km1[hop] = m1;
  }

  const int BS = 256;

  // ws layout (int units): row_ptr[100001] | cnt[100000] | pad | csr int2[NNZ]
  const size_t off_rowptr = 0;
  const size_t off_cnt    = 100001;
  const size_t off_csr    = 200004;                 // *4B = 800016, 16B aligned
  int*  row_ptr = (int*)d_ws + off_rowptr;
  int*  cnt     = (int*)d_ws + off_cnt;
  int2* csr     = (int2*)((int*)d_ws + off_csr);

  k_init<<<(kNTotal * 16 + BS - 1) / BS, BS, 0, stream>>>(ue, ie, out);
  k_zero_cnt<<<(kNTotal + BS - 1) / BS, BS, 0, stream>>>(cnt);
  k_hist<<<(kNnz + BS - 1) / BS, BS, 0, stream>>>(er, cnt);
  k_scan<<<1, 1024, 0, stream>>>(row_ptr, cnt);
  k_scatter<<<(kNnz + BS - 1) / BS, BS, 0, stream>>>(
      er, ec, ev, row_ptr, cnt, csr,
      ke0[0], ke1[0], ke0[1], ke1[1], ke0[2], ke1[2]);

  for (int hop = 0; hop < kHops; ++hop) {
    const float* src = out + (size_t)hop * kD;
    float*       dst = out + (size_t)(hop + 1) * kD;
    k_spmm_csr<<<(kNTotal + 3) / 4, 256, 0, stream>>>(
        row_ptr, csr, src, dst, 1u << (20 + hop), km0[hop], km1[hop]);
  }
}

// Round 5
// 525.140 us; speedup vs baseline: 7.9773x; 1.4107x over previous
//
#include <hip/hip_runtime.h>
#include <cstdint>

namespace {
constexpr int kNUsers = 50000;
constexpr int kNTotal = 100000;        // N = users + items
constexpr int kD = 64;
constexpr int kHops = 3;
constexpr int kNnz = 3200000;
constexpr int kRowStride = (kHops + 1) * kD;     // 256 floats per node in embs
constexpr uint32_t kColMask = (1u << 20) - 1u;   // col in bits 0..19, keep bits 20..22
constexpr int kScanChunk = 1024;                 // elems per scan block
constexpr int kScanBlocks = (kNTotal + kScanChunk - 1) / kScanChunk;  // 98
}

#define ROTL32(v, r) (((v) << (r)) | ((v) >> (32 - (r))))

// JAX threefry2x32, 20 rounds — matches jax/_src/prng.py exactly.
__host__ __device__ inline void tf2x32(uint32_t k0, uint32_t k1,
                                       uint32_t &x0, uint32_t &x1) {
  const uint32_t k2 = k0 ^ k1 ^ 0x1BD11BDAu;
  x0 += k0; x1 += k1;
#define TFR(r) { x0 += x1; x1 = ROTL32(x1, r); x1 ^= x0; }
  TFR(13) TFR(15) TFR(26) TFR(6)
  x0 += k1; x1 += k2 + 1u;
  TFR(17) TFR(29) TFR(16) TFR(24)
  x0 += k2; x1 += k0 + 2u;
  TFR(13) TFR(15) TFR(26) TFR(6)
  x0 += k0; x1 += k1 + 3u;
  TFR(17) TFR(29) TFR(16) TFR(24)
  x0 += k1; x1 += k2 + 4u;
  TFR(13) TFR(15) TFR(26) TFR(6)
  x0 += k2; x1 += k0 + 5u;
#undef TFR
}

// partitionable random_bits for 32-bit draws: counter (0, i), fold x0^x1
__device__ __forceinline__ uint32_t pbits(uint32_t k0, uint32_t k1, uint32_t i) {
  uint32_t x0 = 0u, x1 = i;
  tf2x32(k0, k1, x0, x1);
  return x0 ^ x1;
}

// bits -> U[0,1) exactly like jax.random.uniform (f32): (b>>9)|0x3f800000, -1.0
__device__ __forceinline__ float u01(uint32_t b) {
  return __uint_as_float((b >> 9) | 0x3f800000u) - 1.0f;
}

// embs[:,0,:] = concat(user, item). One thread per (node, float4).
__global__ void k_init(const float* __restrict__ ue, const float* __restrict__ ie,
                       float* __restrict__ out) {
  int t = blockIdx.x * blockDim.x + threadIdx.x;
  if (t >= kNTotal * 16) return;
  int n = t >> 4, c = t & 15;
  float4 v = (n < kNUsers) ? reinterpret_cast<const float4*>(ue)[n * 16 + c]
                           : reinterpret_cast<const float4*>(ie)[(n - kNUsers) * 16 + c];
  reinterpret_cast<float4*>(out)[(size_t)n * (kRowStride / 4) + c] = v;
}

// ---------------- CSR build ----------------
__global__ void k_zero_cnt(int* __restrict__ cnt) {
  int t = blockIdx.x * blockDim.x + threadIdx.x;
  if (t < kNTotal) cnt[t] = 0;
}

__global__ void k_hist(const int* __restrict__ rows, int* __restrict__ cnt) {
  int e = blockIdx.x * blockDim.x + threadIdx.x;
  if (e < kNnz) atomicAdd(&cnt[rows[e]], 1);
}

// scan pass 1: per-block (1024 elems) exclusive scan -> row_ptr; block sum -> bsum
__global__ __launch_bounds__(256) void k_scan1(const int* __restrict__ cnt,
                                               int* __restrict__ row_ptr,
                                               int* __restrict__ bsum) {
  __shared__ int lds[256];
  const int t = threadIdx.x;
  const int base = blockIdx.x * kScanChunk + t * 4;
  int4 c = make_int4(0, 0, 0, 0);
  if (base < kNTotal)                       // kNTotal % 4 == 0, aligned
    c = *reinterpret_cast<const int4*>(cnt + base);
  const int s = c.x + c.y + c.z + c.w;
  lds[t] = s;
  __syncthreads();
  // Hillis-Steele inclusive scan over 256 threads
  for (int off = 1; off < 256; off <<= 1) {
    int add = (t >= off) ? lds[t - off] : 0;
    __syncthreads();
    lds[t] += add;
    __syncthreads();
  }
  if (base < kNTotal) {
    const int excl = lds[t] - s;            // exclusive prefix within block
    int4 o;
    o.x = excl;
    o.y = excl + c.x;
    o.z = excl + c.x + c.y;
    o.w = excl + c.x + c.y + c.z;
    *reinterpret_cast<int4*>(row_ptr + base) = o;
  }
  if (t == 255) bsum[blockIdx.x] = lds[255];
}

// scan pass 2: single block scans bsum[kScanBlocks] (exclusive) in LDS
__global__ void k_scan2(int* __restrict__ bsum) {
  __shared__ int lds[128];
  const int t = threadIdx.x;
  int v = (t < kScanBlocks) ? bsum[t] : 0;
  lds[t] = v;
  __syncthreads();
  for (int off = 1; off < 128; off <<= 1) {
    int add = (t >= off) ? lds[t - off] : 0;
    __syncthreads();
    lds[t] += add;
    __syncthreads();
  }
  if (t < kScanBlocks) bsum[t] = lds[t] - v;   // exclusive
}

// scan pass 3: add block offsets; zero cnt for scatter; set row_ptr[N]
__global__ __launch_bounds__(256) void k_scan3(int* __restrict__ row_ptr,
                                               const int* __restrict__ bsum,
                                               int* __restrict__ cnt) {
  const int t = threadIdx.x;
  const int base = blockIdx.x * kScanChunk + t * 4;
  const int off = bsum[blockIdx.x];
  if (base < kNTotal) {
    int4 o = *reinterpret_cast<int4*>(row_ptr + base);
    o.x += off; o.y += off; o.z += off; o.w += off;
    *reinterpret_cast<int4*>(row_ptr + base) = o;
    *reinterpret_cast<int4*>(cnt + base) = make_int4(0, 0, 0, 0);
  }
  if (blockIdx.x == 0 && t == 0) row_ptr[kNTotal] = kNnz;
}

// packed scatter: one int2 per edge = {col | keepbits<<20, val*2}.
// keep bits for all 3 hops computed here (threefry on original edge id e),
// so SpMM needs no RNG per edge and only ONE dirty line per edge.
__global__ void k_scatter(const int* __restrict__ rows, const int* __restrict__ cols,
                          const float* __restrict__ vals,
                          const int* __restrict__ row_ptr, int* __restrict__ cnt,
                          int2* __restrict__ csr,
                          uint32_t ke0_0, uint32_t ke1_0,
                          uint32_t ke0_1, uint32_t ke1_1,
                          uint32_t ke0_2, uint32_t ke1_2) {
  int e = blockIdx.x * blockDim.x + threadIdx.x;
  if (e >= kNnz) return;
  int r = rows[e];
  int pos = row_ptr[r] + atomicAdd(&cnt[r], 1);
  uint32_t x = (uint32_t)cols[e];
  if (u01(pbits(ke0_0, ke1_0, (uint32_t)e)) >= 0.5f) x |= 1u << 20;
  if (u01(pbits(ke0_1, ke1_1, (uint32_t)e)) >= 0.5f) x |= 1u << 21;
  if (u01(pbits(ke0_2, ke1_2, (uint32_t)e)) >= 0.5f) x |= 1u << 22;
  csr[pos] = make_int2((int)x, __float_as_int(vals[e] * 2.0f));
}

// ---------------- fused SpMM: one wave per row ----------------
// ballot-compacts kept edges into the LDS stage, then a 4-way unrolled
// broadcast+gather loop with 4 independent accumulators (no branch, no RNG).
// Message dropout fused into the single coalesced store.
__global__ __launch_bounds__(256) void k_spmm_csr(
    const int* __restrict__ row_ptr, const int2* __restrict__ csr,
    const float* __restrict__ src, float* __restrict__ dst,
    uint32_t hopbit, uint32_t km0, uint32_t km1) {
  __shared__ int2 stage[4][68];
  const int wave = threadIdx.x >> 6;
  const int lane = threadIdx.x & 63;
  const int r = __builtin_amdgcn_readfirstlane(blockIdx.x * 4 + wave);
  if (r >= kNTotal) return;
  const int start = row_ptr[r], end = row_ptr[r + 1];
  float a0 = 0.f, a1 = 0.f, a2 = 0.f, a3 = 0.f;
  for (int base = start; base < end; base += 64) {
    const int n = min(64, end - base);
    bool keep = false;
    int2 cv = make_int2(0, 0);
    if (lane < n) {
      cv = csr[base + lane];
      keep = ((uint32_t)cv.x & hopbit) != 0u;
    }
    const uint64_t m = __ballot(keep);
    const int k = __popcll(m);
    if (keep) {
      const int slot = __popcll(m & ((1ull << lane) - 1ull));
      stage[wave][slot] = make_int2((int)((uint32_t)cv.x & kColMask), cv.y);
    }
    if (lane < 3) stage[wave][k + lane] = make_int2(0, 0);  // zero-pad for unroll tail
    // wave-synchronous LDS (single wave writes+reads its own stage row)
    for (int j = 0; j < k; j += 4) {
      const int2 e0 = stage[wave][j];
      const int2 e1 = stage[wave][j + 1];
      const int2 e2 = stage[wave][j + 2];
      const int2 e3 = stage[wave][j + 3];
      a0 += __int_as_float(e0.y) * src[(size_t)e0.x * kRowStride + lane];
      a1 += __int_as_float(e1.y) * src[(size_t)e1.x * kRowStride + lane];
      a2 += __int_as_float(e2.y) * src[(size_t)e2.x * kRowStride + lane];
      a3 += __int_as_float(e3.y) * src[(size_t)e3.x * kRowStride + lane];
    }
  }
  const float acc = (a0 + a1) + (a2 + a3);
  // fused message dropout + single coalesced store
  const float u = u01(pbits(km0, km1, (uint32_t)(r * 64 + lane)));
  dst[(size_t)r * kRowStride + lane] = (u < 0.9f) ? acc * (float)(1.0 / 0.9) : 0.0f;
}

extern "C" void kernel_launch(void* const* d_in, const int* in_sizes, int n_in,
                              void* d_out, int out_size, void* d_ws, size_t ws_size,
                              hipStream_t stream) {
  const float* ue = (const float*)d_in[0];
  const float* ie = (const float*)d_in[1];
  const float* ev = (const float*)d_in[2];
  const int*   er = (const int*)d_in[3];
  const int*   ec = (const int*)d_in[4];
  float* out = (float*)d_out;

  // keys: base = key(42) = (0,42); per hop fold_in, then partitionable split:
  // keys[j] = threefry(folded_key, (0, j)).
  uint32_t ke0[kHops], ke1[kHops], km0[kHops], km1[kHops];
  for (int hop = 0; hop < kHops; ++hop) {
    uint32_t f0 = 0u, f1 = (uint32_t)hop;
    tf2x32(0u, 42u, f0, f1);
    uint32_t e0 = 0u, e1 = 0u;
    tf2x32(f0, f1, e0, e1);
    uint32_t m0 = 0u, m1 = 1u;
    tf2x32(f0, f1, m0, m1);
    ke0[hop] = e0; ke1[hop] = e1;
    km0[hop] = m0; km1[hop] = m1;
  }

  const int BS = 256;

  // ws layout (int units):
  // row_ptr[100001] | cnt[100000] | bsum[kScanBlocks] | pad | csr int2[NNZ]
  const size_t off_rowptr = 0;
  const size_t off_cnt    = 100001;
  const size_t off_bsum   = 200001;
  const size_t off_csr    = 200104;                 // *4B, 16B aligned
  int*  row_ptr = (int*)d_ws + off_rowptr;
  int*  cnt     = (int*)d_ws + off_cnt;
  int*  bsum    = (int*)d_ws + off_bsum;
  int2* csr     = (int2*)((int*)d_ws + off_csr);

  k_init<<<(kNTotal * 16 + BS - 1) / BS, BS, 0, stream>>>(ue, ie, out);
  k_zero_cnt<<<(kNTotal + BS - 1) / BS, BS, 0, stream>>>(cnt);
  k_hist<<<(kNnz + BS - 1) / BS, BS, 0, stream>>>(er, cnt);
  k_scan1<<<kScanBlocks, 256, 0, stream>>>(cnt, row_ptr, bsum);
  k_scan2<<<1, 128, 0, stream>>>(bsum);
  k_scan3<<<kScanBlocks, 256, 0, stream>>>(row_ptr, bsum, cnt);
  k_scatter<<<(kNnz + BS - 1) / BS, BS, 0, stream>>>(
      er, ec, ev, row_ptr, cnt, csr,
      ke0[0], ke1[0], ke0[1], ke1[1], ke0[2], ke1[2]);

  for (int hop = 0; hop < kHops; ++hop) {
    const float* src = out + (size_t)hop * kD;
    float*       dst = out + (size_t)(hop + 1) * kD;
    k_spmm_csr<<<(kNTotal + 3) / 4, 256, 0, stream>>>(
        row_ptr, csr, src, dst, 1u << (20 + hop), km0[hop], km1[hop]);
  }
}